// Round 4
// baseline (1566.916 us; speedup 1.0000x reference)
//
#include <hip/hip_runtime.h>

// ---------------------------------------------------------------------------
// MPN (chemprop) on MI355X. bf16 MFMA (16x16x32), fp32 accum.
//   relu(inp + m@W_h) == relu([f_bonds | m] @ [W_i ; W_h])  -> no stored inp.
//   combine pass: tmp[b] = amsg[b2a[b]] - msg[b2revb[b]]  (separate, streamed)
// GEMM: global_load_lds(16B) double-buffered staging, 128M x 160N block,
//       4 waves 2x2, wave tile 64x80 (4x5 frags), swizzled conflict-free LDS.
// Workspace (~367 MiB): wih | wto | fbp | amsg | msgA | msgB
//   message stays in msgA across layers; msgB = combine tmp / concat;
//   hid (fp32, 120 MB) overlays fbp+amsg (contiguous 128 MB).
// ---------------------------------------------------------------------------

#define DEVFN static __device__ __forceinline__

typedef __attribute__((ext_vector_type(8))) __bf16 bf16x8;
typedef __attribute__((ext_vector_type(4))) float floatx4;

DEVFN unsigned short f2bf(float f) {
    unsigned int u = __float_as_uint(f);
    u += 0x7FFFu + ((u >> 16) & 1u);   // RNE
    return (unsigned short)(u >> 16);
}
DEVFN float bf2f(unsigned int u) { return __uint_as_float(u << 16); }

DEVFN unsigned int bfsub2(unsigned int a, unsigned int m) {
    float lo = bf2f(a & 0xffffu) - bf2f(m & 0xffffu);
    float hi = bf2f(a >> 16) - bf2f(m >> 16);
    return (unsigned int)f2bf(lo) | ((unsigned int)f2bf(hi) << 16);
}

// async global(16B per lane) -> LDS(wave-uniform base + lane*16)
DEVFN void gll(const unsigned short* g, void* l) {
    __builtin_amdgcn_global_load_lds(
        (const __attribute__((address_space(1))) unsigned int*)g,
        (__attribute__((address_space(3))) unsigned int*)l, 16, 0, 0);
}

// ---------------------------------------------------------------------------
__global__ __launch_bounds__(256) void dbg_fill(float* out, int n, float v) {
    int t = blockIdx.x * 256 + threadIdx.x;
    if (t < n) out[t] = v;
}

// Wih[320][480]: k<147 -> W_i[k][n]; 160<=k<460 -> W_h[k-160][n]; else 0
__global__ __launch_bounds__(256) void prep_wih(const float* __restrict__ Wi,
                                                const float* __restrict__ Wh,
                                                unsigned short* __restrict__ Wt) {
    int t = blockIdx.x * 256 + threadIdx.x;
    if (t >= 320 * 480) return;
    int n = t / 480, k = t - n * 480;
    float v = 0.f;
    if (n < 300) {
        if (k < 147) v = Wi[k * 300 + n];
        else if (k >= 160 && k < 460) v = Wh[(k - 160) * 300 + n];
    }
    Wt[t] = f2bf(v);
}

// Wto[320][448]: k<300 -> W_o[133+k][n]; 304<=k<437 -> W_o[k-304][n]; else 0
__global__ __launch_bounds__(256) void prep_wto(const float* __restrict__ Wo,
                                                unsigned short* __restrict__ Wt) {
    int t = blockIdx.x * 256 + threadIdx.x;
    if (t >= 320 * 448) return;
    int n = t / 448, k = t - n * 448;
    float v = 0.f;
    if (n < 300) {
        if (k < 300) v = Wo[(133 + k) * 300 + n];
        else if (k >= 304 && k < 437) v = Wo[(k - 304) * 300 + n];
    }
    Wt[t] = f2bf(v);
}

// f_bonds [200000][147] fp32 -> [200000][160] bf16 padded
__global__ __launch_bounds__(256) void pad_bonds(const float* __restrict__ fb,
                                                 unsigned short* __restrict__ out) {
    int t = blockIdx.x * 256 + threadIdx.x;
    if (t >= 200000 * 20) return;
    int b = t / 20, c = t - b * 20;
    unsigned int o[4];
#pragma unroll
    for (int p = 0; p < 4; ++p) {
        int sc = c * 8 + p * 2;
        float v0 = (sc < 147) ? fb[(size_t)b * 147 + sc] : 0.f;
        float v1 = (sc + 1 < 147) ? fb[(size_t)b * 147 + sc + 1] : 0.f;
        o[p] = (unsigned int)f2bf(v0) | ((unsigned int)f2bf(v1) << 16);
    }
    *(uint4*)(out + (size_t)b * 160 + c * 8) = make_uint4(o[0], o[1], o[2], o[3]);
}

// f_atoms [100000][133] fp32 -> concat cols 304..447
__global__ __launch_bounds__(256) void atoms_concat(const float* __restrict__ fa,
                                                    unsigned short* __restrict__ concat) {
    int t = blockIdx.x * 256 + threadIdx.x;
    if (t >= 100000 * 18) return;
    int a = t / 18, c = t - a * 18;
    unsigned int o[4];
#pragma unroll
    for (int p = 0; p < 4; ++p) {
        int sc = c * 8 + p * 2;
        float v0 = (sc < 133) ? fa[(size_t)a * 133 + sc] : 0.f;
        float v1 = (sc + 1 < 133) ? fa[(size_t)a * 133 + sc + 1] : 0.f;
        o[p] = (unsigned int)f2bf(v0) | ((unsigned int)f2bf(v1) << 16);
    }
    *(uint4*)(concat + (size_t)a * 448 + 304 + c * 8) = make_uint4(o[0], o[1], o[2], o[3]);
}

// a_msg[a] = sum_j msg[a2b[a][j]]
template <int CH>
__global__ __launch_bounds__(256) void gather_sum(const unsigned short* __restrict__ msg,
                                                  const int* __restrict__ a2b,
                                                  unsigned short* __restrict__ out,
                                                  int ostride, int nA) {
    int t = blockIdx.x * 256 + threadIdx.x;
    if (t >= nA * CH) return;
    int a = t / CH, c = t - a * CH;
    float s[8] = {0, 0, 0, 0, 0, 0, 0, 0};
#pragma unroll
    for (int j = 0; j < 6; ++j) {
        int b = a2b[a * 6 + j];
        uint4 v = *(const uint4*)(msg + (size_t)b * 320 + c * 8);
        s[0] += bf2f(v.x & 0xffffu); s[1] += bf2f(v.x >> 16);
        s[2] += bf2f(v.y & 0xffffu); s[3] += bf2f(v.y >> 16);
        s[4] += bf2f(v.z & 0xffffu); s[5] += bf2f(v.z >> 16);
        s[6] += bf2f(v.w & 0xffffu); s[7] += bf2f(v.w >> 16);
    }
    unsigned int o[4];
#pragma unroll
    for (int p = 0; p < 4; ++p)
        o[p] = (unsigned int)f2bf(s[2 * p]) | ((unsigned int)f2bf(s[2 * p + 1]) << 16);
    *(uint4*)(out + (size_t)a * ostride + c * 8) = make_uint4(o[0], o[1], o[2], o[3]);
}

// tmp[b] = amsg[b2a[b]] - msg[b2revb[b]]   (bond-message GEMM A operand)
__global__ __launch_bounds__(256) void combine(const unsigned short* __restrict__ amsg,
                                               const unsigned short* __restrict__ msg,
                                               const int* __restrict__ b2a,
                                               const int* __restrict__ b2revb,
                                               unsigned short* __restrict__ out) {
    int t = blockIdx.x * 256 + threadIdx.x;       // 200000 * 40
    if (t >= 200000 * 40) return;
    int b = t / 40, c = t - b * 40;
    int sa = b2a[b], rb = b2revb[b];
    uint4 va = *(const uint4*)(amsg + (size_t)sa * 320 + c * 8);
    uint4 vm = *(const uint4*)(msg + (size_t)rb * 320 + c * 8);
    uint4 o = make_uint4(bfsub2(va.x, vm.x), bfsub2(va.y, vm.y),
                         bfsub2(va.z, vm.z), bfsub2(va.w, vm.w));
    *(uint4*)(out + (size_t)b * 320 + c * 8) = o;
}

// ---------------------------------------------------------------------------
// GEMM: C[M][320] = [A0 | A1] @ Wt^T.  Wt[320][BSTRIDE] k-contiguous rows.
// Block 128M x 160N (grid.y in {0,1}); 4 waves 2x2; wave 64x80 (4x5 frags).
// Staging: global_load_lds 16B/lane.  LDS tiles (per buffer):
//   As [128 rows][64 B], Bs [160 rows][64 B]; quarter p of row r holds global
//   quarter (p ^ r ^ (r>>2))&3  ->  all ds_read_b128 are 2-way (free).
// K-loop per kt: issue(kt+1) -> ds_read frags(kt) -> 20 MFMA -> barrier.
// MODE 0: outp[r*320+col] = relu(acc) bf16
// MODE 2: hid[r*300+col]  = relu(acc + bo[col]) fp32 (col<300, r<M)
// ---------------------------------------------------------------------------
template <int KT0, int KT1, int MODE, int BSTRIDE>
__global__ __launch_bounds__(256, 4) void gemm_k(const unsigned short* __restrict__ A0,
                                                 int a0s,
                                                 const unsigned short* __restrict__ A1,
                                                 int a1s,
                                                 const unsigned short* __restrict__ Wt,
                                                 unsigned short* __restrict__ outp,
                                                 float* __restrict__ hid,
                                                 const float* __restrict__ bo, int M) {
    constexpr int KT = KT0 + KT1;
    __shared__ char lds[2 * 8192 + 2 * 10240];    // As[2][8K] then Bs[2][10K]
    char* As = lds;
    char* Bs = lds + 16384;

    const int tid = threadIdx.x;
    const int lane = tid & 63;
    const int w = tid >> 6;
    const int wm = w & 1, wn = w >> 1;
    const int l16 = lane & 15, quad = lane >> 4;
    const int m0 = blockIdx.x * 128;
    const int n0 = blockIdx.y * 160;

    // ---- staging pointers (per thread, constant over kt) ----
    // swizzled global quarter for this thread's staging unit(s)
    const int qg = ((tid & 3) ^ (tid >> 2) ^ (tid >> 4)) & 3;
    const int r0i = tid >> 2;                      // A rows 0..63 / B rows
    const int gr0 = min(m0 + r0i, M - 1);
    const int gr1 = min(m0 + 64 + r0i, M - 1);
    const unsigned short* pA0a = A0 + (size_t)gr0 * a0s + qg * 8;
    const unsigned short* pA0b = A0 + (size_t)gr1 * a0s + qg * 8;
    const unsigned short* pA1a = (KT1 > 0) ? A1 + (size_t)gr0 * a1s + qg * 8 : A0;
    const unsigned short* pA1b = (KT1 > 0) ? A1 + (size_t)gr1 * a1s + qg * 8 : A0;
    const unsigned short* pB0 = Wt + (size_t)(n0 + r0i) * BSTRIDE + qg * 8;
    const unsigned short* pB1 = Wt + (size_t)(n0 + 64 + r0i) * BSTRIDE + qg * 8;
    const unsigned short* pB2 = (tid < 128)
        ? Wt + (size_t)(n0 + 128 + r0i) * BSTRIDE + qg * 8 : Wt;

    const int wl = w * 1024;                      // wave's 1KB LDS slice offset

    auto issue = [&](int kt, int buf) {
        char* ab = As + buf * 8192;
        char* bb = Bs + buf * 10240;
        if (kt < KT0) {
            gll(pA0a + kt * 32, ab + wl);
            gll(pA0b + kt * 32, ab + 4096 + wl);
        } else {
            gll(pA1a + (kt - KT0) * 32, ab + wl);
            gll(pA1b + (kt - KT0) * 32, ab + 4096 + wl);
        }
        gll(pB0 + kt * 32, bb + wl);
        gll(pB1 + kt * 32, bb + 4096 + wl);
        if (tid < 128) gll(pB2 + kt * 32, bb + 8192 + wl);
    };

    // ---- fragment LDS byte offsets (constant part) ----
    const int swz = ((quad ^ l16 ^ (l16 >> 2)) & 3) * 16;
    int aoff[4], boff[5];
#pragma unroll
    for (int tm = 0; tm < 4; ++tm)
        aoff[tm] = (wm * 64 + tm * 16 + l16) * 64 + swz;
#pragma unroll
    for (int tn = 0; tn < 5; ++tn)
        boff[tn] = (wn * 80 + tn * 16 + l16) * 64 + swz;

    floatx4 acc[4][5];
#pragma unroll
    for (int tm = 0; tm < 4; ++tm)
#pragma unroll
        for (int tn = 0; tn < 5; ++tn) acc[tm][tn] = (floatx4){0.f, 0.f, 0.f, 0.f};

    issue(0, 0);
    __syncthreads();

#pragma unroll
    for (int kt = 0; kt < KT; ++kt) {
        const int buf = kt & 1;
        if (kt + 1 < KT) issue(kt + 1, buf ^ 1);

        const char* ap = As + buf * 8192;
        const char* bp = Bs + buf * 10240;
        bf16x8 av[4];
#pragma unroll
        for (int tm = 0; tm < 4; ++tm)
            av[tm] = *(const bf16x8*)(ap + aoff[tm]);
#pragma unroll
        for (int tn = 0; tn < 5; ++tn) {
            bf16x8 bv = *(const bf16x8*)(bp + boff[tn]);
#pragma unroll
            for (int tm = 0; tm < 4; ++tm)
                acc[tm][tn] = __builtin_amdgcn_mfma_f32_16x16x32_bf16(av[tm], bv, acc[tm][tn], 0, 0, 0);
        }
        __syncthreads();
    }

    // ---- epilogue ----
    float bias[5];
    if (MODE == 2) {
#pragma unroll
        for (int tn = 0; tn < 5; ++tn) {
            int col = n0 + wn * 80 + tn * 16 + l16;
            bias[tn] = (col < 300) ? bo[col] : 0.f;
        }
    }
#pragma unroll
    for (int tm = 0; tm < 4; ++tm) {
        const int r0 = m0 + wm * 64 + tm * 16 + quad * 4;
#pragma unroll
        for (int tn = 0; tn < 5; ++tn) {
            const int col = n0 + wn * 80 + tn * 16 + l16;
#pragma unroll
            for (int i = 0; i < 4; ++i) {
                int r = r0 + i;
                if (r >= M) continue;
                float c = acc[tm][tn][i];
                if (MODE == 2) {
                    if (col < 300) hid[(size_t)r * 300 + col] = fmaxf(c + bias[tn], 0.f);
                } else {
                    outp[(size_t)r * 320 + col] = f2bf(fmaxf(c, 0.f));
                }
            }
        }
    }
}

// ---------------------------------------------------------------------------
// Per-molecule mean. mol_ids sorted -> binary search row range.
// ---------------------------------------------------------------------------
__global__ __launch_bounds__(320) void mean_k(const float* __restrict__ hid,
                                              const int* __restrict__ mol_ids,
                                              float* __restrict__ out, int nA) {
    int mol = blockIdx.x;
    int lo, hi;
    {
        int l = 0, h = nA;
        while (l < h) { int m = (l + h) >> 1; if (mol_ids[m] < mol) l = m + 1; else h = m; }
        lo = l;
    }
    {
        int l = lo, h = nA;
        while (l < h) { int m = (l + h) >> 1; if (mol_ids[m] < mol + 1) l = m + 1; else h = m; }
        hi = l;
    }
    int col = threadIdx.x;
    if (col >= 300) return;
    float s = 0.f;
    for (int a = lo; a < hi; ++a) s += hid[(size_t)a * 300 + col];
    int cnt = hi - lo;
    out[(size_t)mol * 300 + col] = s / (float)(cnt > 0 ? cnt : 1);
}

// ---------------------------------------------------------------------------
extern "C" void kernel_launch(void* const* d_in, const int* in_sizes, int n_in,
                              void* d_out, int out_size, void* d_ws, size_t ws_size,
                              hipStream_t stream) {
    (void)in_sizes; (void)n_in;
    const float* f_atoms = (const float*)d_in[0];
    const float* f_bonds = (const float*)d_in[1];
    const float* W_i     = (const float*)d_in[2];
    const float* W_h     = (const float*)d_in[3];
    const float* W_o     = (const float*)d_in[4];
    const float* b_o     = (const float*)d_in[5];
    const int*   a2b     = (const int*)d_in[6];
    const int*   b2a     = (const int*)d_in[7];
    const int*   b2revb  = (const int*)d_in[8];
    const int*   mol_ids = (const int*)d_in[9];

    const size_t sz_wih  = 320ull * 480 * 2;
    const size_t sz_wto  = 320ull * 448 * 2;
    const size_t sz_fbp  = 200000ull * 160 * 2;
    const size_t sz_amsg = 100000ull * 320 * 2;
    const size_t sz_msg  = 200000ull * 320 * 2;
    const size_t need = sz_wih + sz_wto + sz_fbp + sz_amsg + 2 * sz_msg;

    if (ws_size < need) {
        dbg_fill<<<(out_size + 255) / 256, 256, 0, stream>>>(
            (float*)d_out, out_size, (float)(ws_size >> 20));
        return;
    }

    char* ws = (char*)d_ws;
    unsigned short* wih  = (unsigned short*)(ws);
    unsigned short* wto  = (unsigned short*)(ws + sz_wih);
    unsigned short* fbp  = (unsigned short*)(ws + sz_wih + sz_wto);
    unsigned short* amsg = (unsigned short*)(ws + sz_wih + sz_wto + sz_fbp);
    unsigned short* msgA = (unsigned short*)(ws + sz_wih + sz_wto + sz_fbp + sz_amsg);
    unsigned short* msgB = (unsigned short*)(ws + sz_wih + sz_wto + sz_fbp + sz_amsg + sz_msg);
    unsigned short* concat = msgB;                 // msgB dead after last combine
    float*          hid    = (float*)fbp;          // fbp+amsg contiguous 128MB >= 120MB

    prep_wih<<<600, 256, 0, stream>>>(W_i, W_h, wih);
    prep_wto<<<560, 256, 0, stream>>>(W_o, wto);
    pad_bonds<<<15625, 256, 0, stream>>>(f_bonds, fbp);

    // msgA = relu(f_bonds @ W_i)
    gemm_k<5, 0, 0, 480><<<dim3(1563, 2), 256, 0, stream>>>(
        fbp, 160, nullptr, 0, wih, msgA, nullptr, nullptr, 200000);

    for (int d = 0; d < 3; ++d) {   // DEPTH-1; message stays in msgA
        gather_sum<40><<<15625, 256, 0, stream>>>(msgA, a2b, amsg, 320, 100000);
        combine<<<31250, 256, 0, stream>>>(amsg, msgA, b2a, b2revb, msgB);
        // msgA = relu([fbp | msgB] @ [W_i;W_h])
        gemm_k<5, 10, 0, 480><<<dim3(1563, 2), 256, 0, stream>>>(
            fbp, 160, msgB, 320, wih, msgA, nullptr, nullptr, 200000);
    }

    // final gather into concat cols 0..303 (concat == msgB)
    gather_sum<38><<<14844, 256, 0, stream>>>(msgA, a2b, concat, 448, 100000);
    atoms_concat<<<7032, 256, 0, stream>>>(f_atoms, concat);
    // hid = relu(concat @ W_o + b_o)   (hid overlays fbp+amsg — both dead)
    gemm_k<14, 0, 2, 448><<<dim3(782, 2), 256, 0, stream>>>(
        concat, 448, nullptr, 0, wto, nullptr, hid, b_o, 100000);
    mean_k<<<8192, 320, 0, stream>>>(hid, mol_ids, (float*)d_out, 100000);
}

// Round 5
// 1285.258 us; speedup vs baseline: 1.2191x; 1.2191x over previous
//
#include <hip/hip_runtime.h>

// ---------------------------------------------------------------------------
// MPN (chemprop) on MI355X. bf16 MFMA (16x16x32), fp32 accum.
//   relu(inp + m@W_h) == relu([f_bonds | m] @ [W_i ; W_h])  -> no stored inp.
//   combine pass: tmp[b] = amsg[b2a[b]] - msg[b2revb[b]]  (separate, streamed)
// GEMM: global_load_lds(16B) double-buffered staging, 128M x 160N block,
//       4 waves 2x2, wave tile 64x80 (4x5 frags), swizzled conflict-free LDS.
//       One __syncthreads per k-tile (gll writes LDS directly).
// NOTE: __launch_bounds__(256) ONLY — (256,4) capped the unified VGPR/AGPR
//       budget at ~128, compiler spilled acc to scratch (+215MB HBM writes,
//       VGPR_Count 64). Plain bound -> ~110 regs, no spill, 4 blocks/CU.
// Workspace (~367 MiB): wih | wto | fbp | amsg | msgA | msgB
// ---------------------------------------------------------------------------

#define DEVFN static __device__ __forceinline__

typedef __attribute__((ext_vector_type(8))) __bf16 bf16x8;
typedef __attribute__((ext_vector_type(4))) float floatx4;

DEVFN unsigned short f2bf(float f) {
    unsigned int u = __float_as_uint(f);
    u += 0x7FFFu + ((u >> 16) & 1u);   // RNE
    return (unsigned short)(u >> 16);
}
DEVFN float bf2f(unsigned int u) { return __uint_as_float(u << 16); }

DEVFN unsigned int bfsub2(unsigned int a, unsigned int m) {
    float lo = bf2f(a & 0xffffu) - bf2f(m & 0xffffu);
    float hi = bf2f(a >> 16) - bf2f(m >> 16);
    return (unsigned int)f2bf(lo) | ((unsigned int)f2bf(hi) << 16);
}

// async global(16B per lane) -> LDS(wave-uniform base + lane*16)
DEVFN void gll(const unsigned short* g, void* l) {
    __builtin_amdgcn_global_load_lds(
        (const __attribute__((address_space(1))) unsigned int*)g,
        (__attribute__((address_space(3))) unsigned int*)l, 16, 0, 0);
}

// ---------------------------------------------------------------------------
__global__ __launch_bounds__(256) void dbg_fill(float* out, int n, float v) {
    int t = blockIdx.x * 256 + threadIdx.x;
    if (t < n) out[t] = v;
}

// Wih[320][480]: k<147 -> W_i[k][n]; 160<=k<460 -> W_h[k-160][n]; else 0
__global__ __launch_bounds__(256) void prep_wih(const float* __restrict__ Wi,
                                                const float* __restrict__ Wh,
                                                unsigned short* __restrict__ Wt) {
    int t = blockIdx.x * 256 + threadIdx.x;
    if (t >= 320 * 480) return;
    int n = t / 480, k = t - n * 480;
    float v = 0.f;
    if (n < 300) {
        if (k < 147) v = Wi[k * 300 + n];
        else if (k >= 160 && k < 460) v = Wh[(k - 160) * 300 + n];
    }
    Wt[t] = f2bf(v);
}

// Wto[320][448]: k<300 -> W_o[133+k][n]; 304<=k<437 -> W_o[k-304][n]; else 0
__global__ __launch_bounds__(256) void prep_wto(const float* __restrict__ Wo,
                                                unsigned short* __restrict__ Wt) {
    int t = blockIdx.x * 256 + threadIdx.x;
    if (t >= 320 * 448) return;
    int n = t / 448, k = t - n * 448;
    float v = 0.f;
    if (n < 300) {
        if (k < 300) v = Wo[(133 + k) * 300 + n];
        else if (k >= 304 && k < 437) v = Wo[(k - 304) * 300 + n];
    }
    Wt[t] = f2bf(v);
}

// f_bonds [200000][147] fp32 -> [200000][160] bf16 padded
__global__ __launch_bounds__(256) void pad_bonds(const float* __restrict__ fb,
                                                 unsigned short* __restrict__ out) {
    int t = blockIdx.x * 256 + threadIdx.x;
    if (t >= 200000 * 20) return;
    int b = t / 20, c = t - b * 20;
    unsigned int o[4];
#pragma unroll
    for (int p = 0; p < 4; ++p) {
        int sc = c * 8 + p * 2;
        float v0 = (sc < 147) ? fb[(size_t)b * 147 + sc] : 0.f;
        float v1 = (sc + 1 < 147) ? fb[(size_t)b * 147 + sc + 1] : 0.f;
        o[p] = (unsigned int)f2bf(v0) | ((unsigned int)f2bf(v1) << 16);
    }
    *(uint4*)(out + (size_t)b * 160 + c * 8) = make_uint4(o[0], o[1], o[2], o[3]);
}

// f_atoms [100000][133] fp32 -> concat cols 304..447
__global__ __launch_bounds__(256) void atoms_concat(const float* __restrict__ fa,
                                                    unsigned short* __restrict__ concat) {
    int t = blockIdx.x * 256 + threadIdx.x;
    if (t >= 100000 * 18) return;
    int a = t / 18, c = t - a * 18;
    unsigned int o[4];
#pragma unroll
    for (int p = 0; p < 4; ++p) {
        int sc = c * 8 + p * 2;
        float v0 = (sc < 133) ? fa[(size_t)a * 133 + sc] : 0.f;
        float v1 = (sc + 1 < 133) ? fa[(size_t)a * 133 + sc + 1] : 0.f;
        o[p] = (unsigned int)f2bf(v0) | ((unsigned int)f2bf(v1) << 16);
    }
    *(uint4*)(concat + (size_t)a * 448 + 304 + c * 8) = make_uint4(o[0], o[1], o[2], o[3]);
}

// a_msg[a] = sum_j msg[a2b[a][j]]
template <int CH>
__global__ __launch_bounds__(256) void gather_sum(const unsigned short* __restrict__ msg,
                                                  const int* __restrict__ a2b,
                                                  unsigned short* __restrict__ out,
                                                  int ostride, int nA) {
    int t = blockIdx.x * 256 + threadIdx.x;
    if (t >= nA * CH) return;
    int a = t / CH, c = t - a * CH;
    float s[8] = {0, 0, 0, 0, 0, 0, 0, 0};
#pragma unroll
    for (int j = 0; j < 6; ++j) {
        int b = a2b[a * 6 + j];
        uint4 v = *(const uint4*)(msg + (size_t)b * 320 + c * 8);
        s[0] += bf2f(v.x & 0xffffu); s[1] += bf2f(v.x >> 16);
        s[2] += bf2f(v.y & 0xffffu); s[3] += bf2f(v.y >> 16);
        s[4] += bf2f(v.z & 0xffffu); s[5] += bf2f(v.z >> 16);
        s[6] += bf2f(v.w & 0xffffu); s[7] += bf2f(v.w >> 16);
    }
    unsigned int o[4];
#pragma unroll
    for (int p = 0; p < 4; ++p)
        o[p] = (unsigned int)f2bf(s[2 * p]) | ((unsigned int)f2bf(s[2 * p + 1]) << 16);
    *(uint4*)(out + (size_t)a * ostride + c * 8) = make_uint4(o[0], o[1], o[2], o[3]);
}

// tmp[b] = amsg[b2a[b]] - msg[b2revb[b]]   (bond-message GEMM A operand)
__global__ __launch_bounds__(256) void combine(const unsigned short* __restrict__ amsg,
                                               const unsigned short* __restrict__ msg,
                                               const int* __restrict__ b2a,
                                               const int* __restrict__ b2revb,
                                               unsigned short* __restrict__ out) {
    int t = blockIdx.x * 256 + threadIdx.x;       // 200000 * 40
    if (t >= 200000 * 40) return;
    int b = t / 40, c = t - b * 40;
    int sa = b2a[b], rb = b2revb[b];
    uint4 va = *(const uint4*)(amsg + (size_t)sa * 320 + c * 8);
    uint4 vm = *(const uint4*)(msg + (size_t)rb * 320 + c * 8);
    uint4 o = make_uint4(bfsub2(va.x, vm.x), bfsub2(va.y, vm.y),
                         bfsub2(va.z, vm.z), bfsub2(va.w, vm.w));
    *(uint4*)(out + (size_t)b * 320 + c * 8) = o;
}

// ---------------------------------------------------------------------------
// GEMM: C[M][320] = [A0 | A1] @ Wt^T.  Wt[320][BSTRIDE] k-contiguous rows.
// Block 128M x 160N (grid.y in {0,1}); 4 waves 2x2; wave 64x80 (4x5 frags).
// Staging: global_load_lds 16B/lane.  LDS tiles (per buffer):
//   As [128 rows][64 B], Bs [160 rows][64 B]; quarter p of row r holds global
//   quarter (p ^ r ^ (r>>2))&3  ->  all ds_read_b128 are 2-way (free).
// K-loop per kt: issue(kt+1) -> ds_read frags(kt) -> 20 MFMA -> barrier.
// MODE 0: outp[r*320+col] = relu(acc) bf16
// MODE 2: hid[r*300+col]  = relu(acc + bo[col]) fp32 (col<300, r<M)
// ---------------------------------------------------------------------------
template <int KT0, int KT1, int MODE, int BSTRIDE>
__global__ __launch_bounds__(256) void gemm_k(const unsigned short* __restrict__ A0,
                                              int a0s,
                                              const unsigned short* __restrict__ A1,
                                              int a1s,
                                              const unsigned short* __restrict__ Wt,
                                              unsigned short* __restrict__ outp,
                                              float* __restrict__ hid,
                                              const float* __restrict__ bo, int M) {
    constexpr int KT = KT0 + KT1;
    __shared__ char lds[2 * 8192 + 2 * 10240];    // As[2][8K] then Bs[2][10K]
    char* As = lds;
    char* Bs = lds + 16384;

    const int tid = threadIdx.x;
    const int lane = tid & 63;
    const int w = tid >> 6;
    const int wm = w & 1, wn = w >> 1;
    const int l16 = lane & 15, quad = lane >> 4;
    const int m0 = blockIdx.x * 128;
    const int n0 = blockIdx.y * 160;

    // ---- staging pointers (per thread, constant over kt) ----
    const int qg = ((tid & 3) ^ (tid >> 2) ^ (tid >> 4)) & 3;
    const int r0i = tid >> 2;                      // A rows 0..63 / B rows
    const int gr0 = min(m0 + r0i, M - 1);
    const int gr1 = min(m0 + 64 + r0i, M - 1);
    const unsigned short* pA0a = A0 + (size_t)gr0 * a0s + qg * 8;
    const unsigned short* pA0b = A0 + (size_t)gr1 * a0s + qg * 8;
    const unsigned short* pA1a = (KT1 > 0) ? A1 + (size_t)gr0 * a1s + qg * 8 : A0;
    const unsigned short* pA1b = (KT1 > 0) ? A1 + (size_t)gr1 * a1s + qg * 8 : A0;
    const unsigned short* pB0 = Wt + (size_t)(n0 + r0i) * BSTRIDE + qg * 8;
    const unsigned short* pB1 = Wt + (size_t)(n0 + 64 + r0i) * BSTRIDE + qg * 8;
    const unsigned short* pB2 = (tid < 128)
        ? Wt + (size_t)(n0 + 128 + r0i) * BSTRIDE + qg * 8 : Wt;

    const int wl = w * 1024;                      // wave's 1KB LDS slice offset

    auto issue = [&](int kt, int buf) {
        char* ab = As + buf * 8192;
        char* bb = Bs + buf * 10240;
        if (kt < KT0) {
            gll(pA0a + kt * 32, ab + wl);
            gll(pA0b + kt * 32, ab + 4096 + wl);
        } else {
            gll(pA1a + (kt - KT0) * 32, ab + wl);
            gll(pA1b + (kt - KT0) * 32, ab + 4096 + wl);
        }
        gll(pB0 + kt * 32, bb + wl);
        gll(pB1 + kt * 32, bb + 4096 + wl);
        if (tid < 128) gll(pB2 + kt * 32, bb + 8192 + wl);
    };

    // ---- fragment LDS byte offsets (constant part) ----
    const int swz = ((quad ^ l16 ^ (l16 >> 2)) & 3) * 16;
    int aoff[4], boff[5];
#pragma unroll
    for (int tm = 0; tm < 4; ++tm)
        aoff[tm] = (wm * 64 + tm * 16 + l16) * 64 + swz;
#pragma unroll
    for (int tn = 0; tn < 5; ++tn)
        boff[tn] = (wn * 80 + tn * 16 + l16) * 64 + swz;

    floatx4 acc[4][5];
#pragma unroll
    for (int tm = 0; tm < 4; ++tm)
#pragma unroll
        for (int tn = 0; tn < 5; ++tn) acc[tm][tn] = (floatx4){0.f, 0.f, 0.f, 0.f};

    issue(0, 0);
    __syncthreads();

#pragma unroll
    for (int kt = 0; kt < KT; ++kt) {
        const int buf = kt & 1;
        if (kt + 1 < KT) issue(kt + 1, buf ^ 1);

        const char* ap = As + buf * 8192;
        const char* bp = Bs + buf * 10240;
        bf16x8 av[4];
#pragma unroll
        for (int tm = 0; tm < 4; ++tm)
            av[tm] = *(const bf16x8*)(ap + aoff[tm]);
#pragma unroll
        for (int tn = 0; tn < 5; ++tn) {
            bf16x8 bv = *(const bf16x8*)(bp + boff[tn]);
#pragma unroll
            for (int tm = 0; tm < 4; ++tm)
                acc[tm][tn] = __builtin_amdgcn_mfma_f32_16x16x32_bf16(av[tm], bv, acc[tm][tn], 0, 0, 0);
        }
        __syncthreads();
    }

    // ---- epilogue ----
    float bias[5];
    if (MODE == 2) {
#pragma unroll
        for (int tn = 0; tn < 5; ++tn) {
            int col = n0 + wn * 80 + tn * 16 + l16;
            bias[tn] = (col < 300) ? bo[col] : 0.f;
        }
    }
#pragma unroll
    for (int tm = 0; tm < 4; ++tm) {
        const int r0 = m0 + wm * 64 + tm * 16 + quad * 4;
#pragma unroll
        for (int tn = 0; tn < 5; ++tn) {
            const int col = n0 + wn * 80 + tn * 16 + l16;
#pragma unroll
            for (int i = 0; i < 4; ++i) {
                int r = r0 + i;
                if (r >= M) continue;
                float c = acc[tm][tn][i];
                if (MODE == 2) {
                    if (col < 300) hid[(size_t)r * 300 + col] = fmaxf(c + bias[tn], 0.f);
                } else {
                    outp[(size_t)r * 320 + col] = f2bf(fmaxf(c, 0.f));
                }
            }
        }
    }
}

// ---------------------------------------------------------------------------
// Per-molecule mean. mol_ids sorted -> binary search row range.
// ---------------------------------------------------------------------------
__global__ __launch_bounds__(320) void mean_k(const float* __restrict__ hid,
                                              const int* __restrict__ mol_ids,
                                              float* __restrict__ out, int nA) {
    int mol = blockIdx.x;
    int lo, hi;
    {
        int l = 0, h = nA;
        while (l < h) { int m = (l + h) >> 1; if (mol_ids[m] < mol) l = m + 1; else h = m; }
        lo = l;
    }
    {
        int l = lo, h = nA;
        while (l < h) { int m = (l + h) >> 1; if (mol_ids[m] < mol + 1) l = m + 1; else h = m; }
        hi = l;
    }
    int col = threadIdx.x;
    if (col >= 300) return;
    float s = 0.f;
    for (int a = lo; a < hi; ++a) s += hid[(size_t)a * 300 + col];
    int cnt = hi - lo;
    out[(size_t)mol * 300 + col] = s / (float)(cnt > 0 ? cnt : 1);
}

// ---------------------------------------------------------------------------
extern "C" void kernel_launch(void* const* d_in, const int* in_sizes, int n_in,
                              void* d_out, int out_size, void* d_ws, size_t ws_size,
                              hipStream_t stream) {
    (void)in_sizes; (void)n_in;
    const float* f_atoms = (const float*)d_in[0];
    const float* f_bonds = (const float*)d_in[1];
    const float* W_i     = (const float*)d_in[2];
    const float* W_h     = (const float*)d_in[3];
    const float* W_o     = (const float*)d_in[4];
    const float* b_o     = (const float*)d_in[5];
    const int*   a2b     = (const int*)d_in[6];
    const int*   b2a     = (const int*)d_in[7];
    const int*   b2revb  = (const int*)d_in[8];
    const int*   mol_ids = (const int*)d_in[9];

    const size_t sz_wih  = 320ull * 480 * 2;
    const size_t sz_wto  = 320ull * 448 * 2;
    const size_t sz_fbp  = 200000ull * 160 * 2;
    const size_t sz_amsg = 100000ull * 320 * 2;
    const size_t sz_msg  = 200000ull * 320 * 2;
    const size_t need = sz_wih + sz_wto + sz_fbp + sz_amsg + 2 * sz_msg;

    if (ws_size < need) {
        dbg_fill<<<(out_size + 255) / 256, 256, 0, stream>>>(
            (float*)d_out, out_size, (float)(ws_size >> 20));
        return;
    }

    char* ws = (char*)d_ws;
    unsigned short* wih  = (unsigned short*)(ws);
    unsigned short* wto  = (unsigned short*)(ws + sz_wih);
    unsigned short* fbp  = (unsigned short*)(ws + sz_wih + sz_wto);
    unsigned short* amsg = (unsigned short*)(ws + sz_wih + sz_wto + sz_fbp);
    unsigned short* msgA = (unsigned short*)(ws + sz_wih + sz_wto + sz_fbp + sz_amsg);
    unsigned short* msgB = (unsigned short*)(ws + sz_wih + sz_wto + sz_fbp + sz_amsg + sz_msg);
    unsigned short* concat = msgB;                 // msgB dead after last combine
    float*          hid    = (float*)fbp;          // fbp+amsg contiguous 128MB >= 120MB

    prep_wih<<<600, 256, 0, stream>>>(W_i, W_h, wih);
    prep_wto<<<560, 256, 0, stream>>>(W_o, wto);
    pad_bonds<<<15625, 256, 0, stream>>>(f_bonds, fbp);

    // msgA = relu(f_bonds @ W_i)
    gemm_k<5, 0, 0, 480><<<dim3(1563, 2), 256, 0, stream>>>(
        fbp, 160, nullptr, 0, wih, msgA, nullptr, nullptr, 200000);

    for (int d = 0; d < 3; ++d) {   // DEPTH-1; message stays in msgA
        gather_sum<40><<<15625, 256, 0, stream>>>(msgA, a2b, amsg, 320, 100000);
        combine<<<31250, 256, 0, stream>>>(amsg, msgA, b2a, b2revb, msgB);
        // msgA = relu([fbp | msgB] @ [W_i;W_h])
        gemm_k<5, 10, 0, 480><<<dim3(1563, 2), 256, 0, stream>>>(
            fbp, 160, msgB, 320, wih, msgA, nullptr, nullptr, 200000);
    }

    // final gather into concat cols 0..303 (concat == msgB)
    gather_sum<38><<<14844, 256, 0, stream>>>(msgA, a2b, concat, 448, 100000);
    atoms_concat<<<7032, 256, 0, stream>>>(f_atoms, concat);
    // hid = relu(concat @ W_o + b_o)   (hid overlays fbp+amsg — both dead)
    gemm_k<14, 0, 2, 448><<<dim3(782, 2), 256, 0, stream>>>(
        concat, 448, nullptr, 0, wto, nullptr, hid, b_o, 100000);
    mean_k<<<8192, 320, 0, stream>>>(hid, mol_ids, (float*)d_out, 100000);
}